// Round 7
// baseline (132.126 us; speedup 1.0000x reference)
//
#include <hip/hip_runtime.h>
#include <cmath>

// CapsuleLayer routing, B=64, Ni=2048, Di=16, No=32, Do=16 (fp32 in/out).
// R11: break the barrier-locked serial chain. R9/R10 post-mortem: fused is
// latency-bound; per-iter chain = MFMA -> syncA -> [staging + routing] ->
// syncB -> acc, ~11K cyc/iter at 2 blocks/CU. This round:
//  - WA DOUBLE-buffered (2x32KB): staging of n+1 moves INTO phase 1,
//    concurrent with MFMA reads of the other buffer. Chain becomes
//    max(MFMA, staging) + routing. Barriers stay at 2/iter; all
//    write->read pairs separated by >=1 barrier (proof in comments).
//  - x switches from LDS preload to per-lane register prefetch (the 32KB
//    XL+single-WA no longer fits with double-WA at 2 blocks/CU). 2 KB/iter
//    per block, L1-resident; q>=2 lanes duplicate q<2 addresses (coalesced).
//  - setprio dropped, reduce kernel reverted: R9's proven-best config.
// Kept: 2-way b-split, XOR-swizzled pad-free LDS (conflicts 0), cvt_pk
// split-bf16, (512,4) bounds (only proven spill-free cap), XCD pairing,
// gidx-major partial epilogue.

#define NI 2048
#define NGROUPS 256
#define NPER 8

typedef short bf16x8 __attribute__((ext_vector_type(8)));
typedef float f32x4 __attribute__((ext_vector_type(4)));

static __device__ __forceinline__ unsigned cvt_pk_bf16(float a, float b) {
  unsigned r;
  asm("v_cvt_pk_bf16_f32 %0, %1, %2" : "=v"(r) : "v"(a), "v"(b));
  return r;  // lo16 = bf16(a), hi16 = bf16(b), RNE
}
// fp32 -> (hi bf16x4, lo bf16x4) with hi+lo ~ full precision
static __device__ __forceinline__ void split4_pk(float4 v, uint2& hi, uint2& lo) {
  hi.x = cvt_pk_bf16(v.x, v.y);
  hi.y = cvt_pk_bf16(v.z, v.w);
  float r0 = v.x - __uint_as_float(hi.x << 16);
  float r1 = v.y - __uint_as_float(hi.x & 0xFFFF0000u);
  float r2 = v.z - __uint_as_float(hi.y << 16);
  float r3 = v.w - __uint_as_float(hi.y & 0xFFFF0000u);
  lo.x = cvt_pk_bf16(r0, r1);
  lo.y = cvt_pk_bf16(r2, r3);
}
// dword offset of 16B unit u (0/1) of row r in a rows-of-8-dwords array,
// XOR-swizzled so stride-8 row reads spread across banks (both sides use it).
static __device__ __forceinline__ int swz8(int r, int u) {
  return r * 8 + ((u ^ ((r >> 2) & 1)) << 2);
}

// ---------------- Fused kernel: MFMA + in-block routing + weighted accumulate ----
// grid 512; xcd = bx&7, slot = bx>>3 (0..63); ng = xcd*32 + (slot>>1); bh = slot&1
// (both bh blocks of an ng on one XCD -> W read once per XCD from L2/L3).
// block 512 = 8 waves = (bt = wv&1: 16-b tile of the 32-b half) x (oq = wv>>1:
// o-octet). Wave: o = oq*8 .. oq*8+7, b = bt*16 .. +15.
// A = [W_hi|W_lo] (m=d, K=32 packed split), B = [x_hi],[x_lo] dup along K.
// LDS dword offsets (rows of 8 dwords, swizzled):
#define WA0OFF 0       // buffer 0: 32 o * 32 rows (s*16+d) * 8 = 8192
#define WA1OFF 8192    // buffer 1
#define HOFF  16384    // h[b_local][o]: 32 * 33 = 1056
#define C2OFF 17440    // c2[o][b_local]: 32 * 33 = 1056
#define LDSZ  18496    // 74.0 KB -> 2 blocks/CU
__global__ __launch_bounds__(512, 4) void caps_fused_kernel(
    const float* __restrict__ x, const float* __restrict__ W,
    float* __restrict__ partial)
{
  const int bx = blockIdx.x;
  const int xcd = bx & 7, slot = bx >> 3;
  const int ng = xcd * 32 + (slot >> 1);
  const int bh = slot & 1;
  const int t = threadIdx.x;
  const int wv = t >> 6, l = t & 63;
  const int q = l >> 4, dq = l & 15, qh = q & 1, s_a = q >> 1;
  const int bt = wv & 1, oq = wv >> 1;

  __shared__ __align__(16) float lds[LDSZ];
  float* hS  = lds + HOFF;
  float* c2S = lds + C2OFF;

  float sacc[8][4];
  #pragma unroll
  for (int oo = 0; oo < 8; ++oo)
    { sacc[oo][0] = 0.f; sacc[oo][1] = 0.f; sacc[oo][2] = 0.f; sacc[oo][3] = 0.f; }

  const int n0 = ng * NPER;
  // W staging decomposition: chunk c covers o = c*8 + wv; (d, i4) from t
  const int wd = (t >> 2) & 15, wi4 = t & 3;
  const int wu = wi4 >> 1, wsub = (wi4 & 1) * 2;
  // x per-lane pointer: b = bh*32 + bt*16 + dq, i-base = qh*8
  const float* xptr = x + (size_t)(bh * 32 + bt * 16 + dq) * (NI * 16) + qh * 8;

  // ---- prologue: stage WA0 <- W(n0); prefetch wreg <- W(n0+1), xa/xb <- x(n0) ----
  float4 wreg[4];
  #pragma unroll
  for (int c = 0; c < 4; ++c)
    wreg[c] = *(const float4*)(W + (size_t)n0 * 8192 + c * 2048 + 4 * t);
  float4 xa = *(const float4*)(xptr + n0 * 16);
  float4 xb = *(const float4*)(xptr + n0 * 16 + 4);
  {
    float* WAn = lds + WA0OFF;
    #pragma unroll
    for (int c = 0; c < 4; ++c) {
      uint2 hi, lo;
      split4_pk(wreg[c], hi, lo);
      const int rh = (c * 8 + wv) * 32 + wd;
      *(uint2*)&WAn[swz8(rh, wu) + wsub] = hi;
      *(uint2*)&WAn[swz8(rh + 16, wu) + wsub] = lo;
    }
  }
  #pragma unroll
  for (int c = 0; c < 4; ++c)
    wreg[c] = *(const float4*)(W + (size_t)(n0 + 1) * 8192 + c * 2048 + 4 * t);
  __syncthreads();

  #pragma unroll 1
  for (int nn = 0; nn < NPER; ++nn) {
    float* WAc = lds + ((nn & 1) ? WA1OFF : WA0OFF);
    float* WAn = lds + ((nn & 1) ? WA0OFF : WA1OFF);

    // ---- phase 1a: stage W(nn+1) into the OTHER buffer (overlaps MFMA) ----
    if (nn < NPER - 1) {
      #pragma unroll
      for (int c = 0; c < 4; ++c) {
        uint2 hi, lo;
        split4_pk(wreg[c], hi, lo);
        const int rh = (c * 8 + wv) * 32 + wd;
        *(uint2*)&WAn[swz8(rh, wu) + wsub] = hi;
        *(uint2*)&WAn[swz8(rh + 16, wu) + wsub] = lo;
      }
    }
    // ---- phase 1b: issue global prefetch of W(nn+2) ----
    if (nn < NPER - 2) {
      const size_t nb = (size_t)(n0 + nn + 2);
      #pragma unroll
      for (int c = 0; c < 4; ++c)
        wreg[c] = *(const float4*)(W + nb * 8192 + c * 2048 + 4 * t);
    }

    // ---- phase 1c: build B0/B1 frags from xa/xb, then prefetch x(nn+1) ----
    bf16x8 B0, B1;
    {
      unsigned p0 = cvt_pk_bf16(xa.x, xa.y), p1 = cvt_pk_bf16(xa.z, xa.w);
      unsigned p2 = cvt_pk_bf16(xb.x, xb.y), p3 = cvt_pk_bf16(xb.z, xb.w);
      float r0 = xa.x - __uint_as_float(p0 << 16);
      float r1 = xa.y - __uint_as_float(p0 & 0xFFFF0000u);
      float r2 = xa.z - __uint_as_float(p1 << 16);
      float r3 = xa.w - __uint_as_float(p1 & 0xFFFF0000u);
      float r4 = xb.x - __uint_as_float(p2 << 16);
      float r5 = xb.y - __uint_as_float(p2 & 0xFFFF0000u);
      float r6 = xb.z - __uint_as_float(p3 << 16);
      float r7 = xb.w - __uint_as_float(p3 & 0xFFFF0000u);
      unsigned g0 = cvt_pk_bf16(r0, r1), g1 = cvt_pk_bf16(r2, r3);
      unsigned g2 = cvt_pk_bf16(r4, r5), g3 = cvt_pk_bf16(r6, r7);
      union U { unsigned u[4]; bf16x8 v; };
      U u0; u0.u[0] = p0; u0.u[1] = p1; u0.u[2] = p2; u0.u[3] = p3;
      U u1; u1.u[0] = g0; u1.u[1] = g1; u1.u[2] = g2; u1.u[3] = g3;
      B0 = u0.v;  // x_hi, dup along K
      B1 = u1.v;  // x_lo
    }
    if (nn < NPER - 1) {
      xa = *(const float4*)(xptr + (n0 + nn + 1) * 16);
      xb = *(const float4*)(xptr + (n0 + nn + 1) * 16 + 4);
    }

    // ---- phase 1d: MFMA from WAc; h = row-sum(D) -> hS ----
    f32x4 Dv[8];
    #pragma unroll
    for (int oo = 0; oo < 8; ++oo) {
      const int o = oq * 8 + oo;
      bf16x8 A = *(const bf16x8*)&WAc[swz8(o * 32 + s_a * 16 + dq, qh)];
      f32x4 D = {0.f, 0.f, 0.f, 0.f};
      D = __builtin_amdgcn_mfma_f32_16x16x32_bf16(A, B0, D, 0, 0, 0);
      D = __builtin_amdgcn_mfma_f32_16x16x32_bf16(A, B1, D, 0, 0, 0);
      Dv[oo] = D;
      float hs = D[0] + D[1] + D[2] + D[3];   // sum over d within q-group
      hs += __shfl_xor(hs, 16);
      hs += __shfl_xor(hs, 32);               // sum over q
      if (q == 0) hS[(bt * 16 + dq) * 33 + o] = hs;
    }
    __syncthreads();   // syncA: hS ready; WA[nxt] staged

    // ---- phase 2: routing (proven math): thread (bl = t>>4, op = t&15)
    //      handles o = op and op+16; softmax reduce via 16-lane shuffles ----
    {
      const int bl = t >> 4, op = t & 15;
      const float h0 = hS[bl * 33 + op];
      const float h1 = hS[bl * 33 + op + 16];
      const float b10 = h0 * 0.03125f, b11 = h1 * 0.03125f;
      float mx = fmaxf(b10, b11);
      mx = fmaxf(mx, __shfl_xor(mx, 1)); mx = fmaxf(mx, __shfl_xor(mx, 2));
      mx = fmaxf(mx, __shfl_xor(mx, 4)); mx = fmaxf(mx, __shfl_xor(mx, 8));
      const float e0 = __expf(b10 - mx), e1 = __expf(b11 - mx);
      float S = e0 + e1;
      S += __shfl_xor(S, 1); S += __shfl_xor(S, 2);
      S += __shfl_xor(S, 4); S += __shfl_xor(S, 8);
      const float inv = 1.0f / S;
      const float b20 = b10 + e0 * inv * h0, b21 = b11 + e1 * inv * h1;
      float mx2 = fmaxf(b20, b21);
      mx2 = fmaxf(mx2, __shfl_xor(mx2, 1)); mx2 = fmaxf(mx2, __shfl_xor(mx2, 2));
      mx2 = fmaxf(mx2, __shfl_xor(mx2, 4)); mx2 = fmaxf(mx2, __shfl_xor(mx2, 8));
      const float e20 = __expf(b20 - mx2), e21 = __expf(b21 - mx2);
      float S2 = e20 + e21;
      S2 += __shfl_xor(S2, 1); S2 += __shfl_xor(S2, 2);
      S2 += __shfl_xor(S2, 4); S2 += __shfl_xor(S2, 8);
      const float inv2 = 1.0f / S2;
      c2S[op * 33 + bl] = e20 * inv2;
      c2S[(op + 16) * 33 + bl] = e21 * inv2;
    }
    __syncthreads();   // syncB: c2S ready

    // ---- phase 3: weighted accumulate from retained D ----
    #pragma unroll
    for (int oo = 0; oo < 8; ++oo) {
      const int o = oq * 8 + oo;
      const float c = c2S[o * 33 + bt * 16 + dq];
      sacc[oo][0] += c * Dv[oo][0]; sacc[oo][1] += c * Dv[oo][1];
      sacc[oo][2] += c * Dv[oo][2]; sacc[oo][3] += c * Dv[oo][3];
    }
    // c2S reads here precede the next syncA; next c2S writes come after it.
    // hS writes of P1(nn+1) are separated from P2(nn) reads by syncB above.
  }

  // ---- epilogue: gidx-major, block-contiguous (proven clean-WRITE layout) ----
  // partial[ng][b_global][cell], cell = o*16 + d, d = q*4 + r
  float* pb = partial + (size_t)ng * 32768
            + (size_t)(bh * 32 + bt * 16 + dq) * 512 + q * 4;
  #pragma unroll
  for (int oo = 0; oo < 8; ++oo) {
    const int o = oq * 8 + oo;
    *(float4*)(pb + o * 16)
        = make_float4(sacc[oo][0], sacc[oo][1], sacc[oo][2], sacc[oo][3]);
  }
}

// ---------------- Kernel 2: reduce 256 group-partials + squash (R9 proven) ----
__global__ __launch_bounds__(256) void caps_reduce_kernel(
    const float* __restrict__ partial, float* __restrict__ out)
{
  const int t = threadIdx.x;
  const int w4 = t >> 6, ln = t & 63;
  const int pair = blockIdx.x * 4 + w4;     // (b,o), 2048 total
  const int b = pair >> 5, o = pair & 31;
  const int d = ln & 15, cg = ln >> 4;
  const float* p = partial + (size_t)b * 512 + o * 16 + d;
  float s = 0.f;
  #pragma unroll 8
  for (int gg = cg; gg < NGROUPS; gg += 4) s += p[(size_t)gg * 32768];
  s += __shfl_xor(s, 16); s += __shfl_xor(s, 32);    // over cg
  float s2 = s * s;
  s2 += __shfl_xor(s2, 1); s2 += __shfl_xor(s2, 2);
  s2 += __shfl_xor(s2, 4); s2 += __shfl_xor(s2, 8);  // over d
  float scale = s2 / (1.0f + s2) / sqrtf(s2 + 1e-7f);
  if (ln < 16) out[(size_t)b * 512 + o * 16 + d] = scale * s;
}

extern "C" void kernel_launch(void* const* d_in, const int* in_sizes, int n_in,
                              void* d_out, int out_size, void* d_ws, size_t ws_size,
                              hipStream_t stream) {
  const float* x = (const float*)d_in[0];   // [64,2048,16]
  const float* W = (const float*)d_in[1];   // [1,2048,32,16,16]
  if (in_sizes[0] != 64 * 2048 * 16) { const float* tmp = x; x = W; W = tmp; }
  float* out = (float*)d_out;               // [64,32,16]

  float* partial = (float*)d_ws;            // 256*32768 f32 = 33.5 MB (gidx-major)

  caps_fused_kernel<<<512, 512, 0, stream>>>(x, W, partial);
  caps_reduce_kernel<<<512, 256, 0, stream>>>(partial, out);
}

// Round 8
// 127.001 us; speedup vs baseline: 1.0404x; 1.0404x over previous
//
#include <hip/hip_runtime.h>
#include <cmath>

// CapsuleLayer routing, B=64, Ni=2048, Di=16, No=32, Do=16 (fp32 in/out).
// R12 = R10 structure (proven best-equal: XL x-preload, single WA buffer,
// 2-barrier single-buffer pipeline, W prefetch 2 ahead) with ONE change:
// raw s_barrier + lgkmcnt(0)-only waits instead of __syncthreads().
// R11 post-mortem: __syncthreads emits s_waitcnt vmcnt(0) lgkmcnt(0) before
// s_barrier -> the W prefetch issued just before each barrier is forcibly
// drained EVERY iteration (L3/HBM latency lands in the critical chain;
// 13.4K cyc/iter vs ~2.4K of issue work, VALUBusy 30%). All cross-wave
// communication here is LDS-only (WA, hS, c2S), so lgkmcnt(0)+s_barrier is
// sufficient; global loads are register-destination (wave-private, compiler
// auto-waits before use) -> vmcnt never needs draining at barriers.
// Kept (all verified): 2-way b-split, XOR-swizzled pad-free LDS (conflicts 0),
// cvt_pk split-bf16, (512,4) bounds, XCD pairing, gidx-major partial epilogue,
// R9 reduce kernel.

#define NI 2048
#define NGROUPS 256
#define NPER 8

typedef short bf16x8 __attribute__((ext_vector_type(8)));
typedef float f32x4 __attribute__((ext_vector_type(4)));

static __device__ __forceinline__ unsigned cvt_pk_bf16(float a, float b) {
  unsigned r;
  asm("v_cvt_pk_bf16_f32 %0, %1, %2" : "=v"(r) : "v"(a), "v"(b));
  return r;  // lo16 = bf16(a), hi16 = bf16(b), RNE
}
// fp32 -> (hi bf16x4, lo bf16x4) with hi+lo ~ full precision
static __device__ __forceinline__ void split4_pk(float4 v, uint2& hi, uint2& lo) {
  hi.x = cvt_pk_bf16(v.x, v.y);
  hi.y = cvt_pk_bf16(v.z, v.w);
  float r0 = v.x - __uint_as_float(hi.x << 16);
  float r1 = v.y - __uint_as_float(hi.x & 0xFFFF0000u);
  float r2 = v.z - __uint_as_float(hi.y << 16);
  float r3 = v.w - __uint_as_float(hi.y & 0xFFFF0000u);
  lo.x = cvt_pk_bf16(r0, r1);
  lo.y = cvt_pk_bf16(r2, r3);
}
// dword offset of 16B unit u (0/1) of row r in a rows-of-8-dwords array,
// XOR-swizzled so stride-8 row reads spread across banks (both sides use it).
static __device__ __forceinline__ int swz8(int r, int u) {
  return r * 8 + ((u ^ ((r >> 2) & 1)) << 2);
}
// LDS-only barrier: does NOT drain vmcnt (global prefetches stay in flight).
// All cross-wave data here flows through LDS, ordered by lgkmcnt(0)+s_barrier.
static __device__ __forceinline__ void barrier_lds() {
  asm volatile("s_waitcnt lgkmcnt(0)" ::: "memory");
  __builtin_amdgcn_s_barrier();
  __builtin_amdgcn_sched_barrier(0);   // rule #18: pin ordering after asm wait
}

// ---------------- Fused kernel: MFMA + in-block routing + weighted accumulate ----
// grid 512; xcd = bx&7, slot = bx>>3 (0..63); ng = xcd*32 + (slot>>1); bh = slot&1
// (both bh blocks of an ng on one XCD -> W read once per XCD from L2/L3).
// block 512 = 8 waves = (bt = wv&1: 16-b tile of the 32-b half) x (oq = wv>>1:
// o-octet). Wave: o = oq*8 .. oq*8+7, b = bt*16 .. +15.
// A = [W_hi|W_lo] (m=d, K=32 packed split), B = [x_hi],[x_lo] dup along K.
// LDS dword offsets (rows of 8 dwords, swizzled):
#define WAOFF 0        // 32 o * 32 rows (s*16+d) * 8 = 8192
#define XLOFF 8192     // 8 n * 64 rows (s*32 + b_local) * 8 = 4096 (read-only in loop)
#define HOFF  12288    // h[b_local][o]: 32 * 33 = 1056
#define C2OFF 13344    // c2[o][b_local]: 32 * 33 = 1056
#define LDSZ  14400    // 57.6 KB -> 2 blocks/CU
__global__ __launch_bounds__(512, 4) void caps_fused_kernel(
    const float* __restrict__ x, const float* __restrict__ W,
    float* __restrict__ partial)
{
  const int bx = blockIdx.x;
  const int xcd = bx & 7, slot = bx >> 3;
  const int ng = xcd * 32 + (slot >> 1);
  const int bh = slot & 1;
  const int t = threadIdx.x;
  const int wv = t >> 6, l = t & 63;
  const int q = l >> 4, dq = l & 15, qh = q & 1, s_a = q >> 1;
  const int bt = wv & 1, oq = wv >> 1;

  __shared__ __align__(16) float lds[LDSZ];
  float* WA  = lds + WAOFF;
  float* XL  = lds + XLOFF;
  float* hS  = lds + HOFF;
  float* c2S = lds + C2OFF;

  float sacc[8][4];
  #pragma unroll
  for (int oo = 0; oo < 8; ++oo)
    { sacc[oo][0] = 0.f; sacc[oo][1] = 0.f; sacc[oo][2] = 0.f; sacc[oo][3] = 0.f; }

  const int n0 = ng * NPER;
  // W staging decomposition: chunk c covers o = c*8 + wv; (d, i4) from t
  const int wd = (t >> 2) & 15, wi4 = t & 3;
  const int wu = wi4 >> 1, wsub = (wi4 & 1) * 2;

  // ---- prologue: stage W(n0) + ALL x for the group; then prefetch W(n0+1) ----
  float4 wreg[4];
  #pragma unroll
  for (int c = 0; c < 4; ++c)
    wreg[c] = *(const float4*)(W + (size_t)n0 * 8192 + c * 2048 + 4 * t);

  // x preload: 1024 float4 segments (b 0..31, n 0..7, i4 0..3), 2 per thread
  #pragma unroll
  for (int m = 0; m < 2; ++m) {
    const int idx = m * 512 + t;
    const int pb = idx >> 5, pn = (idx >> 2) & 7, pi4 = idx & 3;
    float4 v = *(const float4*)(x + (size_t)(bh * 32 + pb) * (NI * 16)
                                 + (n0 + pn) * 16 + pi4 * 4);
    uint2 hi, lo;
    split4_pk(v, hi, lo);
    const int pu = pi4 >> 1, psub = (pi4 & 1) * 2;
    float* XLn = XL + pn * 512;
    *(uint2*)&XLn[swz8(pb, pu) + psub] = hi;
    *(uint2*)&XLn[swz8(32 + pb, pu) + psub] = lo;
  }

  #pragma unroll
  for (int c = 0; c < 4; ++c) {
    uint2 hi, lo;
    split4_pk(wreg[c], hi, lo);
    const int rh = (c * 8 + wv) * 32 + wd;
    *(uint2*)&WA[swz8(rh, wu) + wsub] = hi;
    *(uint2*)&WA[swz8(rh + 16, wu) + wsub] = lo;
  }
  barrier_lds();

  {
    const size_t nb = (size_t)(n0 + 1);
    #pragma unroll
    for (int c = 0; c < 4; ++c)
      wreg[c] = *(const float4*)(W + nb * 8192 + c * 2048 + 4 * t);
  }

  #pragma unroll 1
  for (int nn = 0; nn < NPER; ++nn) {
    // ---- phase 1: MFMA from LDS (data nn); h = row-sum(D) -> hS ----
    f32x4 Dv[8];
    {
      const float* XLn = XL + nn * 512;
      bf16x8 B0 = *(const bf16x8*)&XLn[swz8(bt * 16 + dq, qh)];        // x_hi
      bf16x8 B1 = *(const bf16x8*)&XLn[swz8(32 + bt * 16 + dq, qh)];   // x_lo
      #pragma unroll
      for (int oo = 0; oo < 8; ++oo) {
        const int o = oq * 8 + oo;
        bf16x8 A = *(const bf16x8*)&WA[swz8(o * 32 + s_a * 16 + dq, qh)];
        f32x4 D = {0.f, 0.f, 0.f, 0.f};
        D = __builtin_amdgcn_mfma_f32_16x16x32_bf16(A, B0, D, 0, 0, 0);
        D = __builtin_amdgcn_mfma_f32_16x16x32_bf16(A, B1, D, 0, 0, 0);
        Dv[oo] = D;
        float hs = D[0] + D[1] + D[2] + D[3];   // sum over d within q-group
        hs += __shfl_xor(hs, 16);
        hs += __shfl_xor(hs, 32);               // sum over q
        if (q == 0) hS[(bt * 16 + dq) * 33 + o] = hs;
      }
    }
    barrier_lds();   // syncA: hS ready; MFMA ds_reads of WA(nn) complete

    // ---- phase 2a: stage W data nn+1 into WA (pipelined, single buffer) ----
    if (nn < NPER - 1) {
      #pragma unroll
      for (int c = 0; c < 4; ++c) {
        uint2 hi, lo;
        split4_pk(wreg[c], hi, lo);
        const int rh = (c * 8 + wv) * 32 + wd;
        *(uint2*)&WA[swz8(rh, wu) + wsub] = hi;
        *(uint2*)&WA[swz8(rh + 16, wu) + wsub] = lo;
      }
    }

    // ---- phase 2b: routing (proven math): thread (bl = t>>4, op = t&15)
    //      handles o = op and op+16; softmax reduce via 16-lane shuffles ----
    {
      const int bl = t >> 4, op = t & 15;
      const float h0 = hS[bl * 33 + op];
      const float h1 = hS[bl * 33 + op + 16];
      const float b10 = h0 * 0.03125f, b11 = h1 * 0.03125f;
      float mx = fmaxf(b10, b11);
      mx = fmaxf(mx, __shfl_xor(mx, 1)); mx = fmaxf(mx, __shfl_xor(mx, 2));
      mx = fmaxf(mx, __shfl_xor(mx, 4)); mx = fmaxf(mx, __shfl_xor(mx, 8));
      const float e0 = __expf(b10 - mx), e1 = __expf(b11 - mx);
      float S = e0 + e1;
      S += __shfl_xor(S, 1); S += __shfl_xor(S, 2);
      S += __shfl_xor(S, 4); S += __shfl_xor(S, 8);
      const float inv = 1.0f / S;
      const float b20 = b10 + e0 * inv * h0, b21 = b11 + e1 * inv * h1;
      float mx2 = fmaxf(b20, b21);
      mx2 = fmaxf(mx2, __shfl_xor(mx2, 1)); mx2 = fmaxf(mx2, __shfl_xor(mx2, 2));
      mx2 = fmaxf(mx2, __shfl_xor(mx2, 4)); mx2 = fmaxf(mx2, __shfl_xor(mx2, 8));
      const float e20 = __expf(b20 - mx2), e21 = __expf(b21 - mx2);
      float S2 = e20 + e21;
      S2 += __shfl_xor(S2, 1); S2 += __shfl_xor(S2, 2);
      S2 += __shfl_xor(S2, 4); S2 += __shfl_xor(S2, 8);
      const float inv2 = 1.0f / S2;
      c2S[op * 33 + bl] = e20 * inv2;
      c2S[(op + 16) * 33 + bl] = e21 * inv2;
    }

    // ---- phase 2c: issue global prefetch of W for nn+2 (NOT drained at
    //      the barrier below — stays in flight until consumed in P2a(nn+1)) ----
    if (nn < NPER - 2) {
      const size_t nb = (size_t)(n0 + nn + 2);
      #pragma unroll
      for (int c = 0; c < 4; ++c)
        wreg[c] = *(const float4*)(W + nb * 8192 + c * 2048 + 4 * t);
    }
    barrier_lds();   // syncB: c2S ready; WA(nn+1) staged

    // ---- phase 3: weighted accumulate from retained D ----
    #pragma unroll
    for (int oo = 0; oo < 8; ++oo) {
      const int o = oq * 8 + oo;
      const float c = c2S[o * 33 + bt * 16 + dq];
      sacc[oo][0] += c * Dv[oo][0]; sacc[oo][1] += c * Dv[oo][1];
      sacc[oo][2] += c * Dv[oo][2]; sacc[oo][3] += c * Dv[oo][3];
    }
    // c2S reads here precede the next syncA; next c2S writes come after it.
  }

  // ---- epilogue: gidx-major, block-contiguous (proven clean-WRITE layout) ----
  // partial[ng][b_global][cell], cell = o*16 + d, d = q*4 + r
  float* pb = partial + (size_t)ng * 32768
            + (size_t)(bh * 32 + bt * 16 + dq) * 512 + q * 4;
  #pragma unroll
  for (int oo = 0; oo < 8; ++oo) {
    const int o = oq * 8 + oo;
    *(float4*)(pb + o * 16)
        = make_float4(sacc[oo][0], sacc[oo][1], sacc[oo][2], sacc[oo][3]);
  }
}

// ---------------- Kernel 2: reduce 256 group-partials + squash (R9 proven) ----
__global__ __launch_bounds__(256) void caps_reduce_kernel(
    const float* __restrict__ partial, float* __restrict__ out)
{
  const int t = threadIdx.x;
  const int w4 = t >> 6, ln = t & 63;
  const int pair = blockIdx.x * 4 + w4;     // (b,o), 2048 total
  const int b = pair >> 5, o = pair & 31;
  const int d = ln & 15, cg = ln >> 4;
  const float* p = partial + (size_t)b * 512 + o * 16 + d;
  float s = 0.f;
  #pragma unroll 8
  for (int gg = cg; gg < NGROUPS; gg += 4) s += p[(size_t)gg * 32768];
  s += __shfl_xor(s, 16); s += __shfl_xor(s, 32);    // over cg
  float s2 = s * s;
  s2 += __shfl_xor(s2, 1); s2 += __shfl_xor(s2, 2);
  s2 += __shfl_xor(s2, 4); s2 += __shfl_xor(s2, 8);  // over d
  float scale = s2 / (1.0f + s2) / sqrtf(s2 + 1e-7f);
  if (ln < 16) out[(size_t)b * 512 + o * 16 + d] = scale * s;
}

extern "C" void kernel_launch(void* const* d_in, const int* in_sizes, int n_in,
                              void* d_out, int out_size, void* d_ws, size_t ws_size,
                              hipStream_t stream) {
  const float* x = (const float*)d_in[0];   // [64,2048,16]
  const float* W = (const float*)d_in[1];   // [1,2048,32,16,16]
  if (in_sizes[0] != 64 * 2048 * 16) { const float* tmp = x; x = W; W = tmp; }
  float* out = (float*)d_out;               // [64,32,16]

  float* partial = (float*)d_ws;            // 256*32768 f32 = 33.5 MB (gidx-major)

  caps_fused_kernel<<<512, 512, 0, stream>>>(x, W, partial);
  caps_reduce_kernel<<<512, 256, 0, stream>>>(partial, out);
}